// Round 3
// baseline (5924.290 us; speedup 1.0000x reference)
//
#include <hip/hip_runtime.h>
#include <stdint.h>

#define NB 16
#define HH 128
#define WW 128
#define L (HH*WW)        // 16384
#define CIN 3
#define HID 256
#define NC 21
#define CHUNK 256
#define WARM 512
#define NCHUNKS (L/CHUNK)   // 64

// ---------------- K1: conv3x3 -> fp32 -> +b1 -> relu -> conv1x1 -> fp32 -> +b2 ----------------
// Conv accumulations in fp64 (round once to fp32 = correctly rounded); bias adds
// done as fp32 elementwise in the reference's order.
__global__ __launch_bounds__(256) void k_conv(
    const float* __restrict__ x, const float* __restrict__ w1,
    const float* __restrict__ b1, const float* __restrict__ w2,
    const float* __restrict__ b2, float* __restrict__ em)
{
    __shared__ float w1s[HID*27];
    __shared__ float w2s[NC*HID];
    __shared__ float b1s[HID];
    __shared__ float b2s[NC];
    int tid = threadIdx.x;
    for (int i = tid; i < HID*27; i += 256) w1s[i] = w1[i];
    for (int i = tid; i < NC*HID; i += 256) w2s[i] = w2[i];
    if (tid < HID) b1s[tid] = b1[tid];
    if (tid < NC)  b2s[tid] = b2[tid];
    __syncthreads();

    int g  = blockIdx.x * 256 + tid;      // 0..B*L-1
    int b  = g >> 14;
    int t  = g & (L-1);
    int y  = t >> 7;
    int xx = t & (WW-1);

    double p[27];
    const float* xb = x + (size_t)b * CIN * L;
    #pragma unroll
    for (int ic = 0; ic < CIN; ++ic) {
        #pragma unroll
        for (int ky = 0; ky < 3; ++ky) {
            #pragma unroll
            for (int kx = 0; kx < 3; ++kx) {
                int yy = y + ky - 1, xc = xx + kx - 1;
                float v = 0.f;
                if (yy >= 0 && yy < HH && xc >= 0 && xc < WW)
                    v = xb[ic * L + yy * WW + xc];
                p[ic*9 + ky*3 + kx] = (double)v;
            }
        }
    }

    double acc[NC];
    #pragma unroll
    for (int c = 0; c < NC; ++c) acc[c] = 0.0;

    for (int oc = 0; oc < HID; ++oc) {
        double hv = 0.0;                              // conv1 accum (no bias inside)
        #pragma unroll
        for (int j = 0; j < 27; ++j) hv += (double)w1s[oc*27 + j] * p[j];
        float h32 = (float)hv;                        // round conv1 to fp32
        h32 = h32 + b1s[oc];                          // fp32 elementwise bias
        h32 = fmaxf(h32, 0.f);                        // relu (fp32)
        double hd = (double)h32;
        #pragma unroll
        for (int c = 0; c < NC; ++c) acc[c] += (double)w2s[c*HID + oc] * hd;
    }
    float* dst = em + (size_t)g * NC;
    #pragma unroll
    for (int c = 0; c < NC; ++c) {
        float e32 = (float)acc[c];                    // round conv2 to fp32
        dst[c] = e32 + b2s[c];                        // fp32 elementwise bias
    }
}

// ---------------- K2: EXACT sequential fp32 Viterbi forward, one wave per batch ----------------
// Reproduces the reference bit-for-bit given emissions: cand = fl32(fl32(s[p]+trans[p][n]) + e[t][n]),
// exact max, first-index argmax (tree keeps ascending-index subtrees; strict '>' for right side).
__global__ __launch_bounds__(64) void k_viterbi_seq(
    const float* __restrict__ em, const float* __restrict__ start,
    const float* __restrict__ endt, const float* __restrict__ trans,
    uint8_t* __restrict__ bp, int* __restrict__ last_tag)
{
    int b    = blockIdx.x;
    int lane = threadIdx.x;
    int ne   = lane < NC ? lane : NC-1;

    const float* emb = em + (size_t)b * L * NC;
    uint8_t*     bpb = bp + (size_t)b * L * NC;

    float tc[NC];
    #pragma unroll
    for (int pp = 0; pp < NC; ++pp) tc[pp] = trans[pp*NC + ne];

    __shared__ float sb[NC];

    float s[NC];
    #pragma unroll
    for (int j = 0; j < NC; ++j) s[j] = emb[j] + start[j];   // fl32, ref order

    float e1 = emb[(size_t)1*NC + ne];   // e[t=1]
    float e2 = emb[(size_t)2*NC + ne];   // e[t=2]

    #define RED_STEP(nn) { \
        _Pragma("unroll") \
        for (int i = 0; i < ((nn)>>1); ++i) { \
            if (w[2*i+1] > w[2*i]) { w[i] = w[2*i+1]; wi[i] = wi[2*i+1]; } \
            else                   { w[i] = w[2*i];   wi[i] = wi[2*i];   } \
        } \
        if ((nn) & 1) { w[(nn)>>1] = w[(nn)-1]; wi[(nn)>>1] = wi[(nn)-1]; } }

    for (int t = 1; t < L; ++t) {
        float ecur = e1; e1 = e2;
        int tn = (t + 2 < L) ? t + 2 : L - 1;
        e2 = emb[(size_t)tn * NC + ne];

        float w[NC]; int wi[NC];
        #pragma unroll
        for (int pp = 0; pp < NC; ++pp) { w[pp] = (s[pp] + tc[pp]) + ecur; wi[pp] = pp; }
        RED_STEP(21) RED_STEP(11) RED_STEP(6) RED_STEP(3) RED_STEP(2)

        if (lane < NC) {
            bpb[(size_t)t * NC + ne] = (uint8_t)wi[0];
            sb[ne] = w[0];
        }
        __syncthreads();
        #pragma unroll
        for (int j = 0; j < NC; ++j) s[j] = sb[j];
        __syncthreads();
    }
    #undef RED_STEP

    if (lane == 0) {
        float bv = s[0] + endt[0]; int bt = 0;
        #pragma unroll
        for (int j = 1; j < NC; ++j) {
            float v = s[j] + endt[j];
            if (v > bv) { bv = v; bt = j; }
        }
        last_tag[b] = bt;
    }
}

// ---------------- K3: chunk-parallel backtrack (integer, exact; backward chains coalesce) ----------------
__global__ __launch_bounds__(64) void k_backtrack(
    const uint8_t* __restrict__ bp, const int* __restrict__ last_tag,
    int* __restrict__ out)
{
    int blk = blockIdx.x;
    int b   = blk >> 6;
    int k   = blk & (NCHUNKS-1);
    int cs  = k * CHUNK;
    int ce  = cs + CHUNK;
    int sp  = ce - 1 + WARM; if (sp > L-1) sp = L-1;
    int tag = (sp == L-1) ? last_tag[b] : 0;   // exact per-batch seed at sequence end, else arbitrary
    const uint8_t* bpb = bp + (size_t)b * L * NC;
    int* ob = out + (size_t)b * L;
    for (int t = sp;; --t) {
        if (t < ce) { if (threadIdx.x == 0) ob[t] = tag; }
        if (t == cs) break;
        tag = (int)bpb[(size_t)t * NC + tag];
    }
}

extern "C" void kernel_launch(void* const* d_in, const int* in_sizes, int n_in,
                              void* d_out, int out_size, void* d_ws, size_t ws_size,
                              hipStream_t stream) {
    const float* x  = (const float*)d_in[0];
    const float* w1 = (const float*)d_in[1];
    const float* b1 = (const float*)d_in[2];
    const float* w2 = (const float*)d_in[3];
    const float* b2 = (const float*)d_in[4];
    const float* st = (const float*)d_in[5];
    const float* en = (const float*)d_in[6];
    const float* tr = (const float*)d_in[7];
    int* out = (int*)d_out;

    char* ws = (char*)d_ws;
    float*   em = (float*)ws;                                    // 16*16384*21*4 = 22,020,096 B
    uint8_t* bp = (uint8_t*)(ws + (size_t)NB*L*NC*4);            // + 5,505,024 B
    int*     lt = (int*)(ws + (size_t)NB*L*NC*5);                // int[NB], offset 27,525,120 (%4==0)

    k_conv       <<<dim3(NB*L/256),   dim3(256), 0, stream>>>(x, w1, b1, w2, b2, em);
    k_viterbi_seq<<<dim3(NB),         dim3(64),  0, stream>>>(em, st, en, tr, bp, lt);
    k_backtrack  <<<dim3(NB*NCHUNKS), dim3(64),  0, stream>>>(bp, lt, out);
}

// Round 4
// 5028.754 us; speedup vs baseline: 1.1781x; 1.1781x over previous
//
#include <hip/hip_runtime.h>
#include <stdint.h>

#define NB 16
#define HH 128
#define WW 128
#define L (HH*WW)        // 16384
#define CIN 3
#define HID 256
#define NC 21
#define CHUNK 256
#define WARM 512
#define NCHUNKS (L/CHUNK)   // 64
#define T_PER 32            // t's per wave in k_bp

// ---------------- K1: conv3x3 -> fp32 -> +b1 -> relu -> conv1x1 -> fp32 -> +b2 ----------------
// Identical arithmetic to the R3-passing version (fp64 accumulate, ascending j/oc fma chain,
// fp32 elementwise bias in ref order); weights read directly from global (wave-uniform
// addresses -> scalar loads) instead of LDS staging — values bit-identical.
__global__ __launch_bounds__(256) void k_conv(
    const float* __restrict__ x, const float* __restrict__ w1,
    const float* __restrict__ b1, const float* __restrict__ w2,
    const float* __restrict__ b2, float* __restrict__ em)
{
    int tid = threadIdx.x;
    int g  = blockIdx.x * 256 + tid;      // 0..B*L-1
    int b  = g >> 14;
    int t  = g & (L-1);
    int y  = t >> 7;
    int xx = t & (WW-1);

    double p[27];
    const float* xb = x + (size_t)b * CIN * L;
    #pragma unroll
    for (int ic = 0; ic < CIN; ++ic) {
        #pragma unroll
        for (int ky = 0; ky < 3; ++ky) {
            #pragma unroll
            for (int kx = 0; kx < 3; ++kx) {
                int yy = y + ky - 1, xc = xx + kx - 1;
                float v = 0.f;
                if (yy >= 0 && yy < HH && xc >= 0 && xc < WW)
                    v = xb[ic * L + yy * WW + xc];
                p[ic*9 + ky*3 + kx] = (double)v;
            }
        }
    }

    double acc[NC];
    #pragma unroll
    for (int c = 0; c < NC; ++c) acc[c] = 0.0;

    for (int oc = 0; oc < HID; ++oc) {
        double hv = 0.0;                              // conv1 accum
        #pragma unroll
        for (int j = 0; j < 27; ++j) hv += (double)w1[oc*27 + j] * p[j];
        float h32 = (float)hv;                        // round conv1 to fp32
        h32 = h32 + b1[oc];                           // fp32 elementwise bias
        h32 = fmaxf(h32, 0.f);                        // relu (fp32)
        double hd = (double)h32;
        #pragma unroll
        for (int c = 0; c < NC; ++c) acc[c] += (double)w2[c*HID + oc] * hd;
    }
    float* dst = em + (size_t)g * NC;
    #pragma unroll
    for (int c = 0; c < NC; ++c) {
        float e32 = (float)acc[c];                    // round conv2 to fp32
        dst[c] = e32 + b2[c];                         // fp32 elementwise bias
    }
}

// ---------------- K2a: sequential fp32 score recursion (max-only), one wave per batch ----------------
// s'[n] = fl( max_p fl(s[p]+T[p][n]) + e[n] )  — bitwise equal to ref's max_p fl(fl(s+T)+e)
// by monotonicity of RNE rounding. Scores wave-uniform (SGPR) via readlane broadcast;
// no LDS, no barriers. Stores every score vector for the parallel bp pass.
__global__ __launch_bounds__(64) void k_scores(
    const float* __restrict__ em, const float* __restrict__ start,
    const float* __restrict__ endt, const float* __restrict__ trans,
    float* __restrict__ sc, int* __restrict__ last_tag)
{
    int b    = blockIdx.x;
    int lane = threadIdx.x;
    int ne   = lane < NC ? lane : NC-1;

    const float* emb = em + (size_t)b * L * NC;
    float*       scb = sc + (size_t)b * L * NC;

    float tc[NC];
    #pragma unroll
    for (int pp = 0; pp < NC; ++pp) tc[pp] = trans[pp*NC + ne];

    // init: s0[j] = fl(em[0][j] + start[j])  (ref order)
    float v0 = emb[ne] + start[ne];
    if (lane < NC) scb[ne] = v0;
    float s[NC];
    #pragma unroll
    for (int j = 0; j < NC; ++j)
        s[j] = __int_as_float(__builtin_amdgcn_readlane(__float_as_int(v0), j));

    // 4-deep emission prefetch ring
    float ebuf[4];
    #pragma unroll
    for (int t0 = 1; t0 <= 4; ++t0) ebuf[t0 & 3] = emb[(size_t)t0 * NC + ne];

    #define MAXSTEP(nn) { \
        _Pragma("unroll") \
        for (int i = 0; i < ((nn)>>1); ++i) w[i] = fmaxf(w[2*i], w[2*i+1]); \
        if ((nn) & 1) w[(nn)>>1] = w[(nn)-1]; }

    #pragma unroll 4
    for (int t = 1; t < L; ++t) {
        float ecur = ebuf[t & 3];
        int tn = t + 4; if (tn > L-1) tn = L-1;
        ebuf[t & 3] = emb[(size_t)tn * NC + ne];

        float w[NC];
        #pragma unroll
        for (int pp = 0; pp < NC; ++pp) w[pp] = s[pp] + tc[pp];   // fl(s+T), SGPR+VGPR adds
        MAXSTEP(21) MAXSTEP(11) MAXSTEP(6) MAXSTEP(3) MAXSTEP(2)  // exact max (no rounding)
        float best = w[0] + ecur;                                  // fl(max + e)

        if (lane < NC) scb[(size_t)t * NC + ne] = best;

        #pragma unroll
        for (int j = 0; j < NC; ++j)
            s[j] = __int_as_float(__builtin_amdgcn_readlane(__float_as_int(best), j));
    }
    #undef MAXSTEP

    if (lane == 0) {
        float bv = s[0] + endt[0]; int bt = 0;
        #pragma unroll
        for (int j = 1; j < NC; ++j) {
            float v = s[j] + endt[j];
            if (v > bv) { bv = v; bt = j; }
        }
        last_tag[b] = bt;
    }
}

// ---------------- K2b: parallel backpointer recovery ----------------
// bp[t][n] = first p with fl(fl(s_{t-1}[p]+T[p][n])+e[t][n]) == s_t[n]
// (descending-p select chain -> smallest matching p = ref's first-index argmax).
__global__ __launch_bounds__(256) void k_bp(
    const float* __restrict__ em, const float* __restrict__ sc,
    const float* __restrict__ trans, uint8_t* __restrict__ bp)
{
    int wave = threadIdx.x >> 6;
    int lane = threadIdx.x & 63;
    int ne   = lane < NC ? lane : NC-1;

    int bidx  = blockIdx.x;
    int b     = bidx >> 7;                              // 128 blocks per batch
    int tbase = (bidx & 127) * (4*T_PER) + wave*T_PER;  // 128*4*32 = 16384

    const float* emb = em + (size_t)b * L * NC;
    const float* scb = sc + (size_t)b * L * NC;
    uint8_t*     bpb = bp + (size_t)b * L * NC;

    float tc[NC];
    #pragma unroll
    for (int pp = 0; pp < NC; ++pp) tc[pp] = trans[pp*NC + ne];

    for (int t = tbase; t < tbase + T_PER; ++t) {
        if (t == 0) continue;
        float target = scb[(size_t)t * NC + ne];
        float e      = emb[(size_t)t * NC + ne];
        const float* sp = scb + (size_t)(t-1) * NC;
        int fi = 0;
        #pragma unroll
        for (int pp = NC-1; pp >= 0; --pp) {
            float cand = (sp[pp] + tc[pp]) + e;
            if (cand == target) fi = pp;
        }
        if (lane < NC) bpb[(size_t)t * NC + ne] = (uint8_t)fi;
    }
}

// ---------------- K3: chunk-parallel backtrack (integer, exact; backward chains coalesce) ----------------
__global__ __launch_bounds__(64) void k_backtrack(
    const uint8_t* __restrict__ bp, const int* __restrict__ last_tag,
    int* __restrict__ out)
{
    int blk = blockIdx.x;
    int b   = blk >> 6;
    int k   = blk & (NCHUNKS-1);
    int cs  = k * CHUNK;
    int ce  = cs + CHUNK;
    int sp  = ce - 1 + WARM; if (sp > L-1) sp = L-1;
    int tag = (sp == L-1) ? last_tag[b] : 0;
    const uint8_t* bpb = bp + (size_t)b * L * NC;
    int* ob = out + (size_t)b * L;
    for (int t = sp;; --t) {
        if (t < ce) { if (threadIdx.x == 0) ob[t] = tag; }
        if (t == cs) break;
        tag = (int)bpb[(size_t)t * NC + tag];
    }
}

extern "C" void kernel_launch(void* const* d_in, const int* in_sizes, int n_in,
                              void* d_out, int out_size, void* d_ws, size_t ws_size,
                              hipStream_t stream) {
    const float* x  = (const float*)d_in[0];
    const float* w1 = (const float*)d_in[1];
    const float* b1 = (const float*)d_in[2];
    const float* w2 = (const float*)d_in[3];
    const float* b2 = (const float*)d_in[4];
    const float* st = (const float*)d_in[5];
    const float* en = (const float*)d_in[6];
    const float* tr = (const float*)d_in[7];
    int* out = (int*)d_out;

    char* ws = (char*)d_ws;
    float*   em = (float*)ws;                                    // 22,020,096 B
    float*   sc = (float*)(ws + (size_t)NB*L*NC*4);              // 22,020,096 B
    uint8_t* bp = (uint8_t*)(ws + (size_t)NB*L*NC*8);            // 5,505,024 B
    int*     lt = (int*)(ws + (size_t)NB*L*NC*9);                // int[NB]

    k_conv     <<<dim3(NB*L/256),   dim3(256), 0, stream>>>(x, w1, b1, w2, b2, em);
    k_scores   <<<dim3(NB),         dim3(64),  0, stream>>>(em, st, en, tr, sc, lt);
    k_bp       <<<dim3(NB*128),     dim3(256), 0, stream>>>(em, sc, tr, bp);
    k_backtrack<<<dim3(NB*NCHUNKS), dim3(64),  0, stream>>>(bp, lt, out);
}

// Round 5
// 3611.543 us; speedup vs baseline: 1.6404x; 1.3924x over previous
//
#include <hip/hip_runtime.h>
#include <stdint.h>

#define NB 16
#define HH 128
#define WW 128
#define L (HH*WW)        // 16384
#define CIN 3
#define HID 256
#define NC 21
#define CHUNK 256
#define WARM 512
#define NCHUNKS (L/CHUNK)   // 64
#define T_PER 32            // t's per wave in k_bp

// ---------------- K1: conv3x3 -> fp32 -> +b1 -> relu -> conv1x1 -> fp32 -> +b2 ----------------
// fp64 accumulate (round once to fp32 = correctly rounded), fp32 elementwise bias in ref order.
__global__ __launch_bounds__(256) void k_conv(
    const float* __restrict__ x, const float* __restrict__ w1,
    const float* __restrict__ b1, const float* __restrict__ w2,
    const float* __restrict__ b2, float* __restrict__ em)
{
    int tid = threadIdx.x;
    int g  = blockIdx.x * 256 + tid;      // 0..B*L-1
    int b  = g >> 14;
    int t  = g & (L-1);
    int y  = t >> 7;
    int xx = t & (WW-1);

    double p[27];
    const float* xb = x + (size_t)b * CIN * L;
    #pragma unroll
    for (int ic = 0; ic < CIN; ++ic) {
        #pragma unroll
        for (int ky = 0; ky < 3; ++ky) {
            #pragma unroll
            for (int kx = 0; kx < 3; ++kx) {
                int yy = y + ky - 1, xc = xx + kx - 1;
                float v = 0.f;
                if (yy >= 0 && yy < HH && xc >= 0 && xc < WW)
                    v = xb[ic * L + yy * WW + xc];
                p[ic*9 + ky*3 + kx] = (double)v;
            }
        }
    }

    double acc[NC];
    #pragma unroll
    for (int c = 0; c < NC; ++c) acc[c] = 0.0;

    for (int oc = 0; oc < HID; ++oc) {
        double hv = 0.0;                              // conv1 accum
        #pragma unroll
        for (int j = 0; j < 27; ++j) hv += (double)w1[oc*27 + j] * p[j];
        float h32 = (float)hv;                        // round conv1 to fp32
        h32 = h32 + b1[oc];                           // fp32 elementwise bias
        h32 = fmaxf(h32, 0.f);                        // relu (fp32)
        double hd = (double)h32;
        #pragma unroll
        for (int c = 0; c < NC; ++c) acc[c] += (double)w2[c*HID + oc] * hd;
    }
    float* dst = em + (size_t)g * NC;
    #pragma unroll
    for (int c = 0; c < NC; ++c) {
        float e32 = (float)acc[c];                    // round conv2 to fp32
        dst[c] = e32 + b2[c];                         // fp32 elementwise bias
    }
}

// ---------------- K2a: sequential fp32 score recursion (max-only), one wave per batch ----------------
// s'[n] = fl( max_p fl(s[p]+T[p][n]) + e[n] ) — bitwise equal to ref by RNE monotonicity.
// Scores broadcast via readlane (SGPRs); tc pinned in VGPRs via opaque asm (R4's VGPR=28
// showed the compiler rematerialized/spilled the loop body); exec mask set ONCE outside loop.
__global__ __launch_bounds__(64) void k_scores(
    const float* __restrict__ em, const float* __restrict__ start,
    const float* __restrict__ endt, const float* __restrict__ trans,
    float* __restrict__ sc, int* __restrict__ last_tag)
{
    int b    = blockIdx.x;
    int lane = threadIdx.x;

    const float* emb = em + (size_t)b * L * NC;
    float*       scb = sc + (size_t)b * L * NC;

    if (lane < NC) {                     // exec set once for the whole recursion
        float tc[NC];
        #pragma unroll
        for (int pp = 0; pp < NC; ++pp) tc[pp] = trans[pp*NC + lane];
        #pragma unroll
        for (int pp = 0; pp < NC; ++pp) asm volatile("" : "+v"(tc[pp]));  // pin in VGPRs

        // init: s0[j] = fl(em[0][j] + start[j])  (ref order)
        float v0 = emb[lane] + start[lane];
        scb[lane] = v0;
        float s[NC];
        #pragma unroll
        for (int j = 0; j < NC; ++j)
            s[j] = __int_as_float(__builtin_amdgcn_readlane(__float_as_int(v0), j));

        // 4-deep emission prefetch ring
        float ebuf[4];
        #pragma unroll
        for (int t0 = 1; t0 <= 4; ++t0) ebuf[t0 & 3] = emb[(size_t)t0 * NC + lane];

        #pragma unroll 4
        for (int t = 1; t < L; ++t) {
            float ecur = ebuf[t & 3];
            int tn = t + 4; if (tn > L-1) tn = L-1;
            ebuf[t & 3] = emb[(size_t)tn * NC + lane];

            float w[NC];
            #pragma unroll
            for (int pp = 0; pp < NC; ++pp) w[pp] = s[pp] + tc[pp];   // fl(s+T)

            // exact max, 3-way groups -> v_max3_f32, depth 3
            float m[7];
            #pragma unroll
            for (int i = 0; i < 7; ++i)
                m[i] = fmaxf(fmaxf(w[3*i], w[3*i+1]), w[3*i+2]);
            float a0 = fmaxf(fmaxf(m[0], m[1]), m[2]);
            float a1 = fmaxf(fmaxf(m[3], m[4]), m[5]);
            float best = fmaxf(fmaxf(a0, a1), m[6]) + ecur;           // fl(max + e)

            scb[(size_t)t * NC + lane] = best;

            #pragma unroll
            for (int j = 0; j < NC; ++j)
                s[j] = __int_as_float(__builtin_amdgcn_readlane(__float_as_int(best), j));
        }

        if (lane == 0) {
            float bv = s[0] + endt[0]; int bt = 0;
            #pragma unroll
            for (int j = 1; j < NC; ++j) {
                float v = s[j] + endt[j];
                if (v > bv) { bv = v; bt = j; }
            }
            last_tag[b] = bt;
        }
    }
}

// ---------------- K2b: parallel backpointer recovery ----------------
// bp[t][n] = first p with fl(fl(s_{t-1}[p]+T[p][n])+e[t][n]) == s_t[n]
__global__ __launch_bounds__(256) void k_bp(
    const float* __restrict__ em, const float* __restrict__ sc,
    const float* __restrict__ trans, uint8_t* __restrict__ bp)
{
    int wave = threadIdx.x >> 6;
    int lane = threadIdx.x & 63;
    int ne   = lane < NC ? lane : NC-1;

    int bidx  = blockIdx.x;
    int b     = bidx >> 7;                              // 128 blocks per batch
    int tbase = (bidx & 127) * (4*T_PER) + wave*T_PER;  // 128*4*32 = 16384

    const float* emb = em + (size_t)b * L * NC;
    const float* scb = sc + (size_t)b * L * NC;
    uint8_t*     bpb = bp + (size_t)b * L * NC;

    float tc[NC];
    #pragma unroll
    for (int pp = 0; pp < NC; ++pp) tc[pp] = trans[pp*NC + ne];

    for (int t = tbase; t < tbase + T_PER; ++t) {
        if (t == 0) continue;
        float target = scb[(size_t)t * NC + ne];
        float e      = emb[(size_t)t * NC + ne];
        const float* sp = scb + (size_t)(t-1) * NC;
        int fi = 0;
        #pragma unroll
        for (int pp = NC-1; pp >= 0; --pp) {
            float cand = (sp[pp] + tc[pp]) + e;
            if (cand == target) fi = pp;
        }
        if (lane < NC) bpb[(size_t)t * NC + ne] = (uint8_t)fi;
    }
}

// ---------------- K3: chunk-parallel backtrack (integer, exact; backward chains coalesce) ----------------
__global__ __launch_bounds__(64) void k_backtrack(
    const uint8_t* __restrict__ bp, const int* __restrict__ last_tag,
    int* __restrict__ out)
{
    int blk = blockIdx.x;
    int b   = blk >> 6;
    int k   = blk & (NCHUNKS-1);
    int cs  = k * CHUNK;
    int ce  = cs + CHUNK;
    int sp  = ce - 1 + WARM; if (sp > L-1) sp = L-1;
    int tag = (sp == L-1) ? last_tag[b] : 0;
    const uint8_t* bpb = bp + (size_t)b * L * NC;
    int* ob = out + (size_t)b * L;
    for (int t = sp;; --t) {
        if (t < ce) { if (threadIdx.x == 0) ob[t] = tag; }
        if (t == cs) break;
        tag = (int)bpb[(size_t)t * NC + tag];
    }
}

extern "C" void kernel_launch(void* const* d_in, const int* in_sizes, int n_in,
                              void* d_out, int out_size, void* d_ws, size_t ws_size,
                              hipStream_t stream) {
    const float* x  = (const float*)d_in[0];
    const float* w1 = (const float*)d_in[1];
    const float* b1 = (const float*)d_in[2];
    const float* w2 = (const float*)d_in[3];
    const float* b2 = (const float*)d_in[4];
    const float* st = (const float*)d_in[5];
    const float* en = (const float*)d_in[6];
    const float* tr = (const float*)d_in[7];
    int* out = (int*)d_out;

    char* ws = (char*)d_ws;
    float*   em = (float*)ws;                                    // 22,020,096 B
    float*   sc = (float*)(ws + (size_t)NB*L*NC*4);              // 22,020,096 B
    uint8_t* bp = (uint8_t*)(ws + (size_t)NB*L*NC*8);            // 5,505,024 B
    int*     lt = (int*)(ws + (size_t)NB*L*NC*9);                // int[NB]

    k_conv     <<<dim3(NB*L/256),   dim3(256), 0, stream>>>(x, w1, b1, w2, b2, em);
    k_scores   <<<dim3(NB),         dim3(64),  0, stream>>>(em, st, en, tr, sc, lt);
    k_bp       <<<dim3(NB*128),     dim3(256), 0, stream>>>(em, sc, tr, bp);
    k_backtrack<<<dim3(NB*NCHUNKS), dim3(64),  0, stream>>>(bp, lt, out);
}

// Round 6
// 2895.252 us; speedup vs baseline: 2.0462x; 1.2474x over previous
//
#include <hip/hip_runtime.h>
#include <stdint.h>

#define NB 16
#define HH 128
#define WW 128
#define L (HH*WW)        // 16384
#define CIN 3
#define HID 256
#define NC 21
#define CHUNK 256
#define WARM 512
#define NCHUNKS (L/CHUNK)   // 64
#define T_PER 32            // t's per wave in k_bp
#define NPACK (L/4)         // 4096 packs of 4 timesteps

// ---------------- K1: conv -> fp32 emissions, stored TRANSPOSED em_T[b][c][t] ----------------
// fp64 accumulate (round once to fp32 = correctly rounded), fp32 elementwise bias in ref order.
// Arithmetic identical to R3/R4/R5 passing versions; only the store layout changed.
__global__ __launch_bounds__(256) void k_conv(
    const float* __restrict__ x, const float* __restrict__ w1,
    const float* __restrict__ b1, const float* __restrict__ w2,
    const float* __restrict__ b2, float* __restrict__ emT)
{
    int tid = threadIdx.x;
    int g  = blockIdx.x * 256 + tid;      // 0..B*L-1
    int b  = g >> 14;
    int t  = g & (L-1);
    int y  = t >> 7;
    int xx = t & (WW-1);

    double p[27];
    const float* xb = x + (size_t)b * CIN * L;
    #pragma unroll
    for (int ic = 0; ic < CIN; ++ic) {
        #pragma unroll
        for (int ky = 0; ky < 3; ++ky) {
            #pragma unroll
            for (int kx = 0; kx < 3; ++kx) {
                int yy = y + ky - 1, xc = xx + kx - 1;
                float v = 0.f;
                if (yy >= 0 && yy < HH && xc >= 0 && xc < WW)
                    v = xb[ic * L + yy * WW + xc];
                p[ic*9 + ky*3 + kx] = (double)v;
            }
        }
    }

    double acc[NC];
    #pragma unroll
    for (int c = 0; c < NC; ++c) acc[c] = 0.0;

    for (int oc = 0; oc < HID; ++oc) {
        double hv = 0.0;                              // conv1 accum
        #pragma unroll
        for (int j = 0; j < 27; ++j) hv += (double)w1[oc*27 + j] * p[j];
        float h32 = (float)hv;                        // round conv1 to fp32
        h32 = h32 + b1[oc];                           // fp32 elementwise bias
        h32 = fmaxf(h32, 0.f);                        // relu (fp32)
        double hd = (double)h32;
        #pragma unroll
        for (int c = 0; c < NC; ++c) acc[c] += (double)w2[c*HID + oc] * hd;
    }
    float* dstb = emT + (size_t)b * NC * L;
    #pragma unroll
    for (int c = 0; c < NC; ++c) {
        float e32 = (float)acc[c];                    // round conv2 to fp32
        dstb[(size_t)c * L + t] = e32 + b2[c];        // transposed store (coalesced in t)
    }
}

// ---------------- K2a: sequential fp32 score recursion, one wave per batch ----------------
// s'[n] = fl( max_p fl(s[p]+T[p][n]) + e[n] ) — bitwise equal to ref by RNE monotonicity.
// Per 4 steps: ONE float4 emission load (2-deep ring = 8-step lookahead) and ONE float4
// score store (layout sc[b][pack][n][4]) — kills the per-step vmcnt drain of R5.
__global__ __launch_bounds__(64) void k_scores(
    const float* __restrict__ emT, const float* __restrict__ start,
    const float* __restrict__ endt, const float* __restrict__ trans,
    float* __restrict__ sc, int* __restrict__ last_tag)
{
    int b    = blockIdx.x;
    int lane = threadIdx.x;

    if (lane < NC) {
        const float*  er  = emT + ((size_t)b * NC + lane) * L;   // my emission row
        const float4* er4 = (const float4*)er;
        float*        scp = sc + (size_t)b * NC * L;             // 84 floats per pack

        float tc[NC];
        #pragma unroll
        for (int pp = 0; pp < NC; ++pp) tc[pp] = trans[pp*NC + lane];
        #pragma unroll
        for (int pp = 0; pp < NC; ++pp) asm volatile("" : "+v"(tc[pp]));  // pin in VGPRs

        float s[NC];

        #define BCAST(val) { \
            _Pragma("unroll") \
            for (int j = 0; j < NC; ++j) \
                s[j] = __int_as_float(__builtin_amdgcn_readlane(__float_as_int(val), j)); }

        #define STEP(EV, OUT) { \
            float w[NC]; \
            _Pragma("unroll") \
            for (int pp = 0; pp < NC; ++pp) w[pp] = s[pp] + tc[pp];   /* fl(s+T) */ \
            float m[7]; \
            _Pragma("unroll") \
            for (int i = 0; i < 7; ++i) m[i] = fmaxf(fmaxf(w[3*i], w[3*i+1]), w[3*i+2]); \
            float a0 = fmaxf(fmaxf(m[0], m[1]), m[2]); \
            float a1 = fmaxf(fmaxf(m[3], m[4]), m[5]); \
            OUT = fmaxf(fmaxf(a0, a1), m[6]) + (EV);                  /* fl(max+e) */ \
            BCAST(OUT) }

        float4 ebuf0 = er4[0];
        float4 ebuf1 = er4[1];

        // ---- pack 0 (t=0 init + t=1..3) ----
        float v0 = ebuf0.x + start[lane];      // s0 = fl(em[0]+start), ref order
        BCAST(v0)
        float a1v, a2v, a3v;
        {
            float4 ev = ebuf0;
            ebuf0 = er4[2];
            STEP(ev.y, a1v)
            STEP(ev.z, a2v)
            STEP(ev.w, a3v)
            *(float4*)(scp + lane*4) = make_float4(v0, a1v, a2v, a3v);
        }

        // ---- packs 1..4095 ----
        for (int k = 1; k < NPACK; ++k) {
            float4 ev = (k & 1) ? ebuf1 : ebuf0;
            int kp = k + 2; if (kp > NPACK-1) kp = NPACK-1;
            if (k & 1) ebuf1 = er4[kp]; else ebuf0 = er4[kp];

            float b0, b1_, b2_, b3;
            STEP(ev.x, b0)
            STEP(ev.y, b1_)
            STEP(ev.z, b2_)
            STEP(ev.w, b3)
            *(float4*)(scp + k*84 + lane*4) = make_float4(b0, b1_, b2_, b3);
        }
        #undef STEP
        #undef BCAST

        if (lane == 0) {
            float bv = s[0] + endt[0]; int bt = 0;
            #pragma unroll
            for (int j = 1; j < NC; ++j) {
                float v = s[j] + endt[j];
                if (v > bv) { bv = v; bt = j; }
            }
            last_tag[b] = bt;
        }
    }
}

// ---------------- K2b: parallel backpointer recovery (new layouts) ----------------
// bp[t][n] = first p with fl(fl(s_{t-1}[p]+T[p][n])+e[t][n]) == s_t[n]
__global__ __launch_bounds__(256) void k_bp(
    const float* __restrict__ emT, const float* __restrict__ sc,
    const float* __restrict__ trans, uint8_t* __restrict__ bp)
{
    int wave = threadIdx.x >> 6;
    int lane = threadIdx.x & 63;
    int ne   = lane < NC ? lane : NC-1;

    int bidx  = blockIdx.x;
    int b     = bidx >> 7;                              // 128 blocks per batch
    int tbase = (bidx & 127) * (4*T_PER) + wave*T_PER;

    const float* emb = emT + (size_t)b * NC * L;
    const float* scp = sc  + (size_t)b * NC * L;
    uint8_t*     bpb = bp  + (size_t)b * L * NC;

    float tc[NC];
    #pragma unroll
    for (int pp = 0; pp < NC; ++pp) tc[pp] = trans[pp*NC + ne];

    for (int t = tbase; t < tbase + T_PER; ++t) {
        if (t == 0) continue;
        float target = scp[(t>>2)*84 + ne*4 + (t&3)];
        float e      = emb[(size_t)ne * L + t];
        const float* sp = scp + ((t-1)>>2)*84 + ((t-1)&3);
        int fi = 0;
        #pragma unroll
        for (int pp = NC-1; pp >= 0; --pp) {
            float cand = (sp[pp*4] + tc[pp]) + e;
            if (cand == target) fi = pp;
        }
        if (lane < NC) bpb[(size_t)t * NC + ne] = (uint8_t)fi;
    }
}

// ---------------- K3: chunk-parallel backtrack (integer, exact) ----------------
__global__ __launch_bounds__(64) void k_backtrack(
    const uint8_t* __restrict__ bp, const int* __restrict__ last_tag,
    int* __restrict__ out)
{
    int blk = blockIdx.x;
    int b   = blk >> 6;
    int k   = blk & (NCHUNKS-1);
    int cs  = k * CHUNK;
    int ce  = cs + CHUNK;
    int sp  = ce - 1 + WARM; if (sp > L-1) sp = L-1;
    int tag = (sp == L-1) ? last_tag[b] : 0;
    const uint8_t* bpb = bp + (size_t)b * L * NC;
    int* ob = out + (size_t)b * L;
    for (int t = sp;; --t) {
        if (t < ce) { if (threadIdx.x == 0) ob[t] = tag; }
        if (t == cs) break;
        tag = (int)bpb[(size_t)t * NC + tag];
    }
}

extern "C" void kernel_launch(void* const* d_in, const int* in_sizes, int n_in,
                              void* d_out, int out_size, void* d_ws, size_t ws_size,
                              hipStream_t stream) {
    const float* x  = (const float*)d_in[0];
    const float* w1 = (const float*)d_in[1];
    const float* b1 = (const float*)d_in[2];
    const float* w2 = (const float*)d_in[3];
    const float* b2 = (const float*)d_in[4];
    const float* st = (const float*)d_in[5];
    const float* en = (const float*)d_in[6];
    const float* tr = (const float*)d_in[7];
    int* out = (int*)d_out;

    char* ws = (char*)d_ws;
    float*   em = (float*)ws;                                    // em_T: 22,020,096 B
    float*   sc = (float*)(ws + (size_t)NB*L*NC*4);              // packed scores: 22,020,096 B
    uint8_t* bp = (uint8_t*)(ws + (size_t)NB*L*NC*8);            // 5,505,024 B
    int*     lt = (int*)(ws + (size_t)NB*L*NC*9);                // int[NB]

    k_conv     <<<dim3(NB*L/256),   dim3(256), 0, stream>>>(x, w1, b1, w2, b2, em);
    k_scores   <<<dim3(NB),         dim3(64),  0, stream>>>(em, st, en, tr, sc, lt);
    k_bp       <<<dim3(NB*128),     dim3(256), 0, stream>>>(em, sc, tr, bp);
    k_backtrack<<<dim3(NB*NCHUNKS), dim3(64),  0, stream>>>(bp, lt, out);
}